// Round 2
// baseline (615.612 us; speedup 1.0000x reference)
//
#include <hip/hip_runtime.h>
#include <hip/hip_bf16.h>
#include <math.h>

// Problem constants
#define B_    64
#define MAXT  511
#define TP1   512
#define S_    1024
#define H_    4096
#define M_TOTAL (B_*TP1)   // 32768 rows
#define NITER (S_/32)      // 32 K-iterations

typedef __attribute__((ext_vector_type(8))) short  short8;   // 8 bf16 = 4 VGPRs (MFMA A/B frag)
typedef __attribute__((ext_vector_type(4))) float  float4v;  // MFMA C/D frag

// ---- workspace layout (bytes) ----
#define ZBUF_BYTES (M_TOTAL*4*sizeof(float))
#define ACC_OFF    ZBUF_BYTES
#define SBF_OFF    0x81000            // 528384, 4K-aligned
#define SBF_BYTES  ((size_t)M_TOTAL*S_*2)
#define W1T_OFF    (SBF_OFF + SBF_BYTES)

static __device__ __forceinline__ unsigned short f2bf(float f) {
    unsigned int u = __float_as_uint(f);
    u = u + 0x7fffu + ((u >> 16) & 1u);   // round-to-nearest-even
    return (unsigned short)(u >> 16);
}

static __device__ __forceinline__ void load_lds16(const void* g, void* l) {
    // async 16B/lane global->LDS; LDS dest = wave-uniform base + lane*16
    __builtin_amdgcn_global_load_lds(
        (const __attribute__((address_space(1))) unsigned int*)g,
        (__attribute__((address_space(3))) unsigned int*)l,
        16, 0, 0);
}

// ---- pre-pass: fp32 s -> bf16, one row (1024 elems) per 128-thread block.
// Dead rows (t >= lengths[b]) are skipped: their tiles either get skipped in
// the GEMM or produce garbage-but-finite rows never read downstream.
__global__ __launch_bounds__(128) void cvt_s_kernel(const float* __restrict__ s,
                                                    const int* __restrict__ lengths,
                                                    unsigned short* __restrict__ out) {
    int row = blockIdx.x;
    int b = row >> 9, t = row & 511;
    if (t >= lengths[b] && t < TP1 - 1) return;          // dead row (t==511 never used either)
    if (t >= lengths[b]) return;
    size_t idx = (size_t)row * S_ + threadIdx.x * 8;
    float4v f0 = *(const float4v*)(s + idx);
    float4v f1 = *(const float4v*)(s + idx + 4);
    short8 o;
    o[0] = (short)f2bf(f0[0]); o[1] = (short)f2bf(f0[1]);
    o[2] = (short)f2bf(f0[2]); o[3] = (short)f2bf(f0[3]);
    o[4] = (short)f2bf(f1[0]); o[5] = (short)f2bf(f1[1]);
    o[6] = (short)f2bf(f1[2]); o[7] = (short)f2bf(f1[3]);
    *(short8*)(out + idx) = o;
}

// ---- pre-pass: W1 (S x H fp32) -> W1T (H x S bf16), LDS-tiled transpose ----
__global__ void cvt_w1t_kernel(const float* __restrict__ W1, unsigned short* __restrict__ W1T) {
    __shared__ float tile[32][33];
    int h0 = blockIdx.x * 32;   // H dim
    int k0 = blockIdx.y * 32;   // S dim
    int tx = threadIdx.x & 31, ty = threadIdx.x >> 5;  // 32 x 8
    for (int r = ty; r < 32; r += 8)
        tile[r][tx] = W1[(size_t)(k0 + r) * H_ + h0 + tx];
    __syncthreads();
    for (int r = ty; r < 32; r += 8)
        W1T[(size_t)(h0 + r) * S_ + k0 + tx] = f2bf(tile[tx][r]);
}

// ---- main fused GEMM: z[row][0..3] += sum_n relu(s@W1 + b1)[row][n] * W2[n][0..3] ----
// 128x128 tile, BK=32, double-buffered LDS, ONE barrier per K-iter:
// loads for iter k+1 are issued right after the barrier and fly during iter-k MFMAs,
// so the compiler's vmcnt(0) drain at the next barrier is nearly free.
__global__ __launch_bounds__(256) void gemm_fused_kernel(
        const unsigned short* __restrict__ Sb,    // M x S bf16
        const unsigned short* __restrict__ W1T,   // H x S bf16
        const float* __restrict__ b1,             // H
        const float* __restrict__ W2,             // H x 32 fp32 (cols 0..3 used)
        const int*   __restrict__ lengths,        // B
        float*       __restrict__ zbuf)           // M x 4
{
    int ntile = blockIdx.x;          // 0..31  (H/128)
    int mtile = blockIdx.y;          // 0..255 (M/128)
    int b  = mtile >> 2;
    int t0 = (mtile & 3) * 128;
    if (lengths[b] <= t0) return;    // whole tile masked out

    int m0 = mtile * 128;
    int n0 = ntile * 128;

    __shared__ unsigned short smemA[2 * 128 * 32];   // 2 x 8 KB
    __shared__ unsigned short smemB[2 * 128 * 32];   // 2 x 8 KB

    int tid  = threadIdx.x;
    int wid  = tid >> 6;
    int lane = tid & 63;
    int lane15 = lane & 15;
    int quad   = lane >> 4;
    int wave_m = (wid >> 1) * 64;
    int wave_n = (wid & 1) * 64;

    // --- staging: chunk c = p*256 + tid; m=c>>2, slot cp=c&3,
    //     global k-chunk q = cp ^ ((m>>1)&3)  (XOR swizzle -> 2-way-free LDS reads)
    int cA0 = tid, cA1 = tid + 256;
    int mA0 = cA0 >> 2, cp0 = cA0 & 3, q0 = cp0 ^ ((mA0 >> 1) & 3);
    int mA1 = cA1 >> 2, cp1 = cA1 & 3, q1 = cp1 ^ ((mA1 >> 1) & 3);

    const char* gA0 = (const char*)Sb  + (size_t)(m0 + mA0) * (S_*2) + q0 * 16;
    const char* gA1 = (const char*)Sb  + (size_t)(m0 + mA1) * (S_*2) + q1 * 16;
    const char* gB0 = (const char*)W1T + (size_t)(n0 + mA0) * (S_*2) + q0 * 16;
    const char* gB1 = (const char*)W1T + (size_t)(n0 + mA1) * (S_*2) + q1 * 16;
    char* lA0 = (char*)smemA + (size_t)(wid * 64) * 16;
    char* lA1 = (char*)smemA + (size_t)(256 + wid * 64) * 16;
    char* lB0 = (char*)smemB + (size_t)(wid * 64) * 16;
    char* lB1 = (char*)smemB + (size_t)(256 + wid * 64) * 16;

    // --- fragment read offsets within a buffer (in shorts) ---
    int aOff[4], bOff[4];
#pragma unroll
    for (int s = 0; s < 4; s++) {
        int ml = wave_m + s * 16 + lane15;
        int ca = quad ^ ((ml >> 1) & 3);
        aOff[s] = ml * 32 + ca * 8;
        int nl = wave_n + s * 16 + lane15;
        int cb = quad ^ ((nl >> 1) & 3);
        bOff[s] = nl * 32 + cb * 8;
    }

    float4v acc[4][4] = {};

    // prologue: stage buffer 0
    load_lds16(gA0, lA0);
    load_lds16(gA1, lA1);
    load_lds16(gB0, lB0);
    load_lds16(gB1, lB1);
    gA0 += 64; gA1 += 64; gB0 += 64; gB1 += 64;

#pragma unroll 4
    for (int k = 0; k < NITER; k++) {
        int cur = k & 1;
        __syncthreads();                 // buf(cur) staged; buf(cur^1) reads from k-1 done
        if (k + 1 < NITER) {
            int nb = (cur ^ 1) * 8192;   // byte offset of next buffer
            load_lds16(gA0, lA0 + nb);
            load_lds16(gA1, lA1 + nb);
            load_lds16(gB0, lB0 + nb);
            load_lds16(gB1, lB1 + nb);
            gA0 += 64; gA1 += 64; gB0 += 64; gB1 += 64;
        }
        const unsigned short* aP = smemA + cur * 4096;
        const unsigned short* bP = smemB + cur * 4096;
        short8 af[4], bf[4];
#pragma unroll
        for (int s = 0; s < 4; s++) {
            af[s] = *(const short8*)(aP + aOff[s]);
            bf[s] = *(const short8*)(bP + bOff[s]);
        }
#pragma unroll
        for (int i = 0; i < 4; i++)
#pragma unroll
            for (int j = 0; j < 4; j++)
                acc[i][j] = __builtin_amdgcn_mfma_f32_16x16x32_bf16(af[i], bf[j], acc[i][j], 0, 0, 0);
    }

    // --- fused epilogue: relu(h) @ W2[:,0:4], shuffle-reduce over the wave's 64 n, atomicAdd ---
    float4v w2r[4];
    float   b1v[4];
#pragma unroll
    for (int ns = 0; ns < 4; ns++) {
        int n_g = n0 + wave_n + ns * 16 + lane15;
        w2r[ns] = *(const float4v*)(W2 + (size_t)n_g * 32);
        b1v[ns] = b1[n_g];
    }
#pragma unroll
    for (int ms = 0; ms < 4; ms++) {
        float p[4][4];
#pragma unroll
        for (int r = 0; r < 4; r++)
#pragma unroll
            for (int c = 0; c < 4; c++) p[r][c] = 0.f;
#pragma unroll
        for (int ns = 0; ns < 4; ns++) {
            float4v av = acc[ms][ns];
#pragma unroll
            for (int r = 0; r < 4; r++) {
                float h = av[r] + b1v[ns];
                h = h > 0.f ? h : 0.f;
                p[r][0] += h * w2r[ns][0];
                p[r][1] += h * w2r[ns][1];
                p[r][2] += h * w2r[ns][2];
                p[r][3] += h * w2r[ns][3];
            }
        }
#pragma unroll
        for (int off = 1; off < 16; off <<= 1)
#pragma unroll
            for (int r = 0; r < 4; r++)
#pragma unroll
                for (int c = 0; c < 4; c++)
                    p[r][c] += __shfl_xor(p[r][c], off);
        if (lane15 < 4) {
            int c = lane15;
#pragma unroll
            for (int r = 0; r < 4; r++) {
                int mg = m0 + wave_m + ms * 16 + quad * 4 + r;
                atomicAdd(&zbuf[(size_t)mg * 4 + c], p[r][c]);
            }
        }
    }
}

// ---- log-softmax gather + masked sum. grid (B, 4) x 128 threads ----
__global__ __launch_bounds__(128) void reduce_logp_kernel(
        const float* __restrict__ zbuf,
        const int*   __restrict__ actions,
        const int*   __restrict__ lengths,
        const float* __restrict__ b2,
        float*       __restrict__ acc)
{
    int b = blockIdx.x;
    int t = blockIdx.y * 128 + threadIdx.x;
    int len = lengths[b];
    float local = 0.f;
    if (t < MAXT && t < len) {
        int row = b * TP1 + t;
        float4v z = *(const float4v*)(zbuf + (size_t)row * 4);
        float z0 = z[0] + b2[0], z1 = z[1] + b2[1], z2 = z[2] + b2[2], z3 = z[3] + b2[3];
        float mx = fmaxf(fmaxf(z0, z1), fmaxf(z2, z3));
        float se = expf(z0 - mx) + expf(z1 - mx) + expf(z2 - mx) + expf(z3 - mx);
        int a = actions[b * MAXT + t];
        float za = (a == 0) ? z0 : (a == 1) ? z1 : (a == 2) ? z2 : z3;
        local += (za - mx) - logf(se);
    }
#pragma unroll
    for (int off = 32; off > 0; off >>= 1) local += __shfl_xor(local, off);
    __shared__ float wsum[2];
    if ((threadIdx.x & 63) == 0) wsum[threadIdx.x >> 6] = local;
    __syncthreads();
    if (threadIdx.x == 0) atomicAdd(acc, wsum[0] + wsum[1]);
}

__global__ void finalize_kernel(const float* __restrict__ acc, float* __restrict__ out) {
    out[0] = -acc[0];
}

extern "C" void kernel_launch(void* const* d_in, const int* in_sizes, int n_in,
                              void* d_out, int out_size, void* d_ws, size_t ws_size,
                              hipStream_t stream) {
    const float* s       = (const float*)d_in[0];  // (64,512,1024) fp32
    const int*   actions = (const int*)  d_in[1];  // (64,511)
    const int*   lengths = (const int*)  d_in[2];  // (64,)
    const float* W1      = (const float*)d_in[3];  // (1024,4096)
    const float* b1      = (const float*)d_in[4];  // (4096,)
    const float* W2      = (const float*)d_in[5];  // (4096,32)
    const float* b2      = (const float*)d_in[6];  // (32,)

    char* ws = (char*)d_ws;
    float*          zbuf = (float*)ws;
    float*          acc  = (float*)(ws + ACC_OFF);
    unsigned short* Sb   = (unsigned short*)(ws + SBF_OFF);
    unsigned short* W1T  = (unsigned short*)(ws + W1T_OFF);

    // zero z-buffer + accumulator (ws is poisoned 0xAA before every launch)
    hipMemsetAsync(ws, 0, ZBUF_BYTES + 256, stream);

    // s -> bf16 (live rows only)
    cvt_s_kernel<<<dim3(M_TOTAL), 128, 0, stream>>>(s, lengths, Sb);
    // W1 -> bf16 transposed (H x S)
    cvt_w1t_kernel<<<dim3(H_ / 32, S_ / 32), 256, 0, stream>>>(W1, W1T);
    // fused GEMM + relu + W2[:,0:4] projection
    gemm_fused_kernel<<<dim3(H_ / 128, M_TOTAL / 128), 256, 0, stream>>>(
        Sb, W1T, b1, W2, lengths, zbuf);
    // log-softmax gather + masked sum
    reduce_logp_kernel<<<dim3(B_, 4), 128, 0, stream>>>(zbuf, actions, lengths, b2, acc);
    finalize_kernel<<<dim3(1), 1, 0, stream>>>(acc, (float*)d_out);
}

// Round 3
// 529.741 us; speedup vs baseline: 1.1621x; 1.1621x over previous
//
#include <hip/hip_runtime.h>
#include <hip/hip_bf16.h>
#include <math.h>

// Problem constants
#define B_    64
#define MAXT  511
#define TP1   512
#define S_    1024
#define H_    4096
#define M_TOTAL (B_*TP1)   // 32768 rows
#define NITER (S_/32)      // 32 K-iterations

typedef __attribute__((ext_vector_type(8))) short  short8;   // 8 bf16 = 4 VGPRs (MFMA A/B frag)
typedef __attribute__((ext_vector_type(4))) float  float4v;  // MFMA C/D frag

// ---- workspace layout (bytes) ----
#define ZBUF_BYTES (M_TOTAL*4*sizeof(float))
#define ACC_OFF    ZBUF_BYTES
#define SBF_OFF    0x81000            // 528384, 4K-aligned
#define SBF_BYTES  ((size_t)M_TOTAL*S_*2)
#define W1T_OFF    (SBF_OFF + SBF_BYTES)

static __device__ __forceinline__ unsigned short f2bf(float f) {
    unsigned int u = __float_as_uint(f);
    u = u + 0x7fffu + ((u >> 16) & 1u);   // round-to-nearest-even
    return (unsigned short)(u >> 16);
}

// ---- pre-pass: fp32 s -> bf16, one live row (1024 elems) per 128-thread block ----
__global__ __launch_bounds__(128) void cvt_s_kernel(const float* __restrict__ s,
                                                    const int* __restrict__ lengths,
                                                    unsigned short* __restrict__ out) {
    int row = blockIdx.x;
    int b = row >> 9, t = row & 511;
    if (t >= lengths[b]) return;   // dead row: tile skipped or value never read downstream
    size_t idx = (size_t)row * S_ + threadIdx.x * 8;
    float4v f0 = *(const float4v*)(s + idx);
    float4v f1 = *(const float4v*)(s + idx + 4);
    short8 o;
    o[0] = (short)f2bf(f0[0]); o[1] = (short)f2bf(f0[1]);
    o[2] = (short)f2bf(f0[2]); o[3] = (short)f2bf(f0[3]);
    o[4] = (short)f2bf(f1[0]); o[5] = (short)f2bf(f1[1]);
    o[6] = (short)f2bf(f1[2]); o[7] = (short)f2bf(f1[3]);
    *(short8*)(out + idx) = o;
}

// ---- pre-pass: W1 (S x H fp32) -> W1T (H x S bf16), LDS-tiled transpose ----
__global__ void cvt_w1t_kernel(const float* __restrict__ W1, unsigned short* __restrict__ W1T) {
    __shared__ float tile[32][33];
    int h0 = blockIdx.x * 32;   // H dim
    int k0 = blockIdx.y * 32;   // S dim
    int tx = threadIdx.x & 31, ty = threadIdx.x >> 5;  // 32 x 8
    for (int r = ty; r < 32; r += 8)
        tile[r][tx] = W1[(size_t)(k0 + r) * H_ + h0 + tx];
    __syncthreads();
    for (int r = ty; r < 32; r += 8)
        W1T[(size_t)(h0 + r) * S_ + k0 + tx] = f2bf(tile[tx][r]);
}

// ---- main fused GEMM ----
// 128x128 tile, BK=32. Staging = buffer_load->VGPR->ds_write (NOT global_load_lds):
// plain register loads carry no LDS-visibility hazard, so s_barrier needs no vmcnt
// drain -- global loads for iter k+2 stay in flight across the barrier and are
// awaited only by iter k+1's ds_write (fine-grained vmcnt). One barrier per iter,
// double-buffered LDS, loop unrolled x2 for static buffer indices.
__global__ __launch_bounds__(256) void gemm_fused_kernel(
        const unsigned short* __restrict__ Sb,    // M x S bf16
        const unsigned short* __restrict__ W1T,   // H x S bf16
        const float* __restrict__ b1,             // H
        const float* __restrict__ W2,             // H x 32 fp32 (cols 0..3 used)
        const int*   __restrict__ lengths,        // B
        float*       __restrict__ zbuf)           // M x 4
{
    int ntile = blockIdx.x;          // 0..31  (H/128)
    int mtile = blockIdx.y;          // 0..255 (M/128)
    int b  = mtile >> 2;
    int t0 = (mtile & 3) * 128;
    if (lengths[b] <= t0) return;    // whole tile masked out

    int m0 = mtile * 128;
    int n0 = ntile * 128;

    __shared__ unsigned short smemA[2 * 128 * 32];   // 2 x 8 KB
    __shared__ unsigned short smemB[2 * 128 * 32];   // 2 x 8 KB

    int tid  = threadIdx.x;
    int wid  = tid >> 6;
    int lane = tid & 63;
    int lane15 = lane & 15;
    int quad   = lane >> 4;
    int wave_m = (wid >> 1) * 64;
    int wave_n = (wid & 1) * 64;

    // staging chunk map: chunk c -> row m=c>>2, slot cp=c&3, global k-chunk
    // q = cp ^ ((m>>1)&3)  (XOR swizzle -> 2-way-free LDS access)
    int cA0 = tid, cA1 = tid + 256;
    int mA0 = cA0 >> 2, cp0 = cA0 & 3, q0 = cp0 ^ ((mA0 >> 1) & 3);
    int mA1 = cA1 >> 2, cp1 = cA1 & 3, q1 = cp1 ^ ((mA1 >> 1) & 3);

    const char* gA0 = (const char*)Sb  + (size_t)(m0 + mA0) * (S_*2) + q0 * 16;
    const char* gA1 = (const char*)Sb  + (size_t)(m0 + mA1) * (S_*2) + q1 * 16;
    const char* gB0 = (const char*)W1T + (size_t)(n0 + mA0) * (S_*2) + q0 * 16;
    const char* gB1 = (const char*)W1T + (size_t)(n0 + mA1) * (S_*2) + q1 * 16;
    char* lwA0 = (char*)smemA + cA0 * 16;   // buf0 write addrs; buf1 = +8192
    char* lwA1 = (char*)smemA + cA1 * 16;
    char* lwB0 = (char*)smemB + cA0 * 16;
    char* lwB1 = (char*)smemB + cA1 * 16;

    // fragment read offsets within a buffer (in shorts)
    int aOff[4], bOff[4];
#pragma unroll
    for (int s = 0; s < 4; s++) {
        int ml = wave_m + s * 16 + lane15;
        aOff[s] = ml * 32 + (quad ^ ((ml >> 1) & 3)) * 8;
        int nl = wave_n + s * 16 + lane15;
        bOff[s] = nl * 32 + (quad ^ ((nl >> 1) & 3)) * 8;
    }

    float4v acc[4][4] = {};
    short8 rA0[2], rA1[2], rB0[2], rB1[2];   // register staging, 2 sets

    // ---- prologue: set0 = j=0 -> ds_write buf0; set1 = j=1 (in flight) ----
    rA0[0] = *(const short8*)gA0; rA1[0] = *(const short8*)gA1;
    rB0[0] = *(const short8*)gB0; rB1[0] = *(const short8*)gB1;
    gA0 += 64; gA1 += 64; gB0 += 64; gB1 += 64;
    *(short8*)lwA0 = rA0[0]; *(short8*)lwA1 = rA1[0];
    *(short8*)lwB0 = rB0[0]; *(short8*)lwB1 = rB1[0];
    rA0[1] = *(const short8*)gA0; rA1[1] = *(const short8*)gA1;
    rB0[1] = *(const short8*)gB0; rB1[1] = *(const short8*)gB1;
    gA0 += 64; gA1 += 64; gB0 += 64; gB1 += 64;

    for (int k = 0; k < NITER; k += 2) {
        // ---- even sub-iter: compute buf0 (j=k), write set1 (j=k+1) -> buf1,
        //      load set0 <- j=k+2 (stays in flight across this AND next barrier's work)
        __syncthreads();
        if (k + 2 < NITER) {
            rA0[0] = *(const short8*)gA0; rA1[0] = *(const short8*)gA1;
            rB0[0] = *(const short8*)gB0; rB1[0] = *(const short8*)gB1;
            gA0 += 64; gA1 += 64; gB0 += 64; gB1 += 64;
        }
        *(short8*)(lwA0 + 8192) = rA0[1]; *(short8*)(lwA1 + 8192) = rA1[1];
        *(short8*)(lwB0 + 8192) = rB0[1]; *(short8*)(lwB1 + 8192) = rB1[1];
        {
            const unsigned short* aP = smemA;
            const unsigned short* bP = smemB;
            short8 af[4], bf[4];
#pragma unroll
            for (int s = 0; s < 4; s++) {
                af[s] = *(const short8*)(aP + aOff[s]);
                bf[s] = *(const short8*)(bP + bOff[s]);
            }
#pragma unroll
            for (int i = 0; i < 4; i++)
#pragma unroll
                for (int j = 0; j < 4; j++)
                    acc[i][j] = __builtin_amdgcn_mfma_f32_16x16x32_bf16(af[i], bf[j], acc[i][j], 0, 0, 0);
        }
        // ---- odd sub-iter: compute buf1 (j=k+1), write set0 (j=k+2) -> buf0,
        //      load set1 <- j=k+3
        __syncthreads();
        if (k + 3 < NITER) {
            rA0[1] = *(const short8*)gA0; rA1[1] = *(const short8*)gA1;
            rB0[1] = *(const short8*)gB0; rB1[1] = *(const short8*)gB1;
            gA0 += 64; gA1 += 64; gB0 += 64; gB1 += 64;
        }
        if (k + 2 < NITER) {
            *(short8*)lwA0 = rA0[0]; *(short8*)lwA1 = rA1[0];
            *(short8*)lwB0 = rB0[0]; *(short8*)lwB1 = rB1[0];
        }
        {
            const unsigned short* aP = smemA + 4096;
            const unsigned short* bP = smemB + 4096;
            short8 af[4], bf[4];
#pragma unroll
            for (int s = 0; s < 4; s++) {
                af[s] = *(const short8*)(aP + aOff[s]);
                bf[s] = *(const short8*)(bP + bOff[s]);
            }
#pragma unroll
            for (int i = 0; i < 4; i++)
#pragma unroll
                for (int j = 0; j < 4; j++)
                    acc[i][j] = __builtin_amdgcn_mfma_f32_16x16x32_bf16(af[i], bf[j], acc[i][j], 0, 0, 0);
        }
    }

    // ---- fused epilogue: relu(h) @ W2[:,0:4], shuffle-reduce, atomicAdd ----
    float4v w2r[4];
    float   b1v[4];
#pragma unroll
    for (int ns = 0; ns < 4; ns++) {
        int n_g = n0 + wave_n + ns * 16 + lane15;
        w2r[ns] = *(const float4v*)(W2 + (size_t)n_g * 32);
        b1v[ns] = b1[n_g];
    }
#pragma unroll
    for (int ms = 0; ms < 4; ms++) {
        float p[4][4];
#pragma unroll
        for (int r = 0; r < 4; r++)
#pragma unroll
            for (int c = 0; c < 4; c++) p[r][c] = 0.f;
#pragma unroll
        for (int ns = 0; ns < 4; ns++) {
            float4v av = acc[ms][ns];
#pragma unroll
            for (int r = 0; r < 4; r++) {
                float h = av[r] + b1v[ns];
                h = h > 0.f ? h : 0.f;
                p[r][0] += h * w2r[ns][0];
                p[r][1] += h * w2r[ns][1];
                p[r][2] += h * w2r[ns][2];
                p[r][3] += h * w2r[ns][3];
            }
        }
#pragma unroll
        for (int off = 1; off < 16; off <<= 1)
#pragma unroll
            for (int r = 0; r < 4; r++)
#pragma unroll
                for (int c = 0; c < 4; c++)
                    p[r][c] += __shfl_xor(p[r][c], off);
        if (lane15 < 4) {
            int c = lane15;
#pragma unroll
            for (int r = 0; r < 4; r++) {
                int mg = m0 + wave_m + ms * 16 + quad * 4 + r;
                atomicAdd(&zbuf[(size_t)mg * 4 + c], p[r][c]);
            }
        }
    }
}

// ---- log-softmax gather + masked sum. grid (B, 4) x 128 threads ----
__global__ __launch_bounds__(128) void reduce_logp_kernel(
        const float* __restrict__ zbuf,
        const int*   __restrict__ actions,
        const int*   __restrict__ lengths,
        const float* __restrict__ b2,
        float*       __restrict__ acc)
{
    int b = blockIdx.x;
    int t = blockIdx.y * 128 + threadIdx.x;
    int len = lengths[b];
    float local = 0.f;
    if (t < MAXT && t < len) {
        int row = b * TP1 + t;
        float4v z = *(const float4v*)(zbuf + (size_t)row * 4);
        float z0 = z[0] + b2[0], z1 = z[1] + b2[1], z2 = z[2] + b2[2], z3 = z[3] + b2[3];
        float mx = fmaxf(fmaxf(z0, z1), fmaxf(z2, z3));
        float se = expf(z0 - mx) + expf(z1 - mx) + expf(z2 - mx) + expf(z3 - mx);
        int a = actions[b * MAXT + t];
        float za = (a == 0) ? z0 : (a == 1) ? z1 : (a == 2) ? z2 : z3;
        local += (za - mx) - logf(se);
    }
#pragma unroll
    for (int off = 32; off > 0; off >>= 1) local += __shfl_xor(local, off);
    __shared__ float wsum[2];
    if ((threadIdx.x & 63) == 0) wsum[threadIdx.x >> 6] = local;
    __syncthreads();
    if (threadIdx.x == 0) atomicAdd(acc, wsum[0] + wsum[1]);
}

__global__ void finalize_kernel(const float* __restrict__ acc, float* __restrict__ out) {
    out[0] = -acc[0];
}

extern "C" void kernel_launch(void* const* d_in, const int* in_sizes, int n_in,
                              void* d_out, int out_size, void* d_ws, size_t ws_size,
                              hipStream_t stream) {
    const float* s       = (const float*)d_in[0];  // (64,512,1024) fp32
    const int*   actions = (const int*)  d_in[1];  // (64,511)
    const int*   lengths = (const int*)  d_in[2];  // (64,)
    const float* W1      = (const float*)d_in[3];  // (1024,4096)
    const float* b1      = (const float*)d_in[4];  // (4096,)
    const float* W2      = (const float*)d_in[5];  // (4096,32)
    const float* b2      = (const float*)d_in[6];  // (32,)

    char* ws = (char*)d_ws;
    float*          zbuf = (float*)ws;
    float*          acc  = (float*)(ws + ACC_OFF);
    unsigned short* Sb   = (unsigned short*)(ws + SBF_OFF);
    unsigned short* W1T  = (unsigned short*)(ws + W1T_OFF);

    // zero z-buffer + accumulator (ws is poisoned 0xAA before every launch)
    hipMemsetAsync(ws, 0, ZBUF_BYTES + 256, stream);

    // s -> bf16 (live rows only)
    cvt_s_kernel<<<dim3(M_TOTAL), 128, 0, stream>>>(s, lengths, Sb);
    // W1 -> bf16 transposed (H x S)
    cvt_w1t_kernel<<<dim3(H_ / 32, S_ / 32), 256, 0, stream>>>(W1, W1T);
    // fused GEMM + relu + W2[:,0:4] projection
    gemm_fused_kernel<<<dim3(H_ / 128, M_TOTAL / 128), 256, 0, stream>>>(
        Sb, W1T, b1, W2, lengths, zbuf);
    // log-softmax gather + masked sum
    reduce_logp_kernel<<<dim3(B_, 4), 128, 0, stream>>>(zbuf, actions, lengths, b2, acc);
    finalize_kernel<<<dim3(1), 1, 0, stream>>>(acc, (float*)d_out);
}

// Round 5
// 476.692 us; speedup vs baseline: 1.2914x; 1.1113x over previous
//
#include <hip/hip_runtime.h>
#include <hip/hip_bf16.h>
#include <math.h>

// Problem constants
#define B_    64
#define MAXT  511
#define TP1   512
#define S_    1024
#define H_    4096
#define M_TOTAL (B_*TP1)   // 32768 rows
#define NITER (S_/32)      // 32 K-iterations

typedef __attribute__((ext_vector_type(8))) short  short8;   // 8 bf16 = 4 VGPRs (MFMA A/B frag)
typedef __attribute__((ext_vector_type(4))) float  float4v;  // MFMA C/D frag

// ---- workspace layout (bytes) ----
// zbuf [0, 512KB) -- Sb MUST start past it (R3 bug: 0x1000 overlapped zbuf)
#define ZBUF_BYTES ((size_t)M_TOTAL*4*sizeof(float))   // 524288
#define SBF_OFF    0x81000                             // 528384 >= ZBUF_BYTES
#define SBF_BYTES  ((size_t)M_TOTAL*S_*2)
#define W1T_OFF    (SBF_OFF + SBF_BYTES)

static __device__ __forceinline__ unsigned short f2bf(float f) {
    unsigned int u = __float_as_uint(f);
    u = u + 0x7fffu + ((u >> 16) & 1u);   // round-to-nearest-even
    return (unsigned short)(u >> 16);
}

// ---- merged pre-pass ----
// blocks [0,16384): s fp32 -> bf16, two live rows per block (wave-uniform skip)
// blocks [16384,16384+4096): W1 (S x H fp32) -> W1T (H x S bf16) 32x32 LDS transpose
__global__ __launch_bounds__(256) void prep_kernel(const float* __restrict__ s,
                                                   const float* __restrict__ W1,
                                                   const int*   __restrict__ lengths,
                                                   unsigned short* __restrict__ Sb,
                                                   unsigned short* __restrict__ W1T) {
    int bid = blockIdx.x;
    if (bid < 16384) {
        int row = 2 * bid + (threadIdx.x >> 7);          // waves 0,1 -> row; waves 2,3 -> row+1
        int b = row >> 9, t = row & 511;
        if (t >= lengths[b]) return;                     // dead row: never read downstream
        size_t idx = (size_t)row * S_ + (threadIdx.x & 127) * 8;
        float4v f0 = *(const float4v*)(s + idx);
        float4v f1 = *(const float4v*)(s + idx + 4);
        short8 o;
        o[0] = (short)f2bf(f0[0]); o[1] = (short)f2bf(f0[1]);
        o[2] = (short)f2bf(f0[2]); o[3] = (short)f2bf(f0[3]);
        o[4] = (short)f2bf(f1[0]); o[5] = (short)f2bf(f1[1]);
        o[6] = (short)f2bf(f1[2]); o[7] = (short)f2bf(f1[3]);
        *(short8*)(Sb + idx) = o;
    } else {
        __shared__ float tile[32][33];
        int tb = bid - 16384;
        int h0 = (tb & 127) * 32;                        // H dim
        int k0 = (tb >> 7) * 32;                         // S dim
        int tx = threadIdx.x & 31, ty = threadIdx.x >> 5; // 32 x 8
        for (int r = ty; r < 32; r += 8)
            tile[r][tx] = W1[(size_t)(k0 + r) * H_ + h0 + tx];
        __syncthreads();
        for (int r = ty; r < 32; r += 8)
            W1T[(size_t)(h0 + r) * S_ + k0 + tx] = f2bf(tile[tx][r]);
    }
}

// ---- main fused GEMM ----
// 128x128 tile, BK=32, buffer_load->VGPR->ds_write staging (no vmcnt drain at
// barriers), 3 register sets = prefetch distance 2 (~600 cyc in flight, covers L3),
// full 32-iter unroll for static set/buffer indices.
// XCD swizzle: xcd = id&7 owns ntiles [4x,4x+4) -> 1 MB of W1T stays L2-resident;
// the 4 blocks sharing an A-tile are consecutive slots on the same XCD.
__global__ __launch_bounds__(256, 4) void gemm_fused_kernel(
        const unsigned short* __restrict__ Sb,    // M x S bf16
        const unsigned short* __restrict__ W1T,   // H x S bf16
        const float* __restrict__ b1,             // H
        const float* __restrict__ W2,             // H x 32 fp32 (cols 0..3 used)
        const int*   __restrict__ lengths,        // B
        float*       __restrict__ zbuf)           // M x 4
{
    int id   = blockIdx.x;
    int xcd  = id & 7;
    int slot = id >> 3;                  // 0..1023
    int ntile = xcd * 4 + (slot & 3);    // 0..31
    int mtile = slot >> 2;               // 0..255

    int b  = mtile >> 2;
    int t0 = (mtile & 3) * 128;
    if (lengths[b] <= t0) return;        // whole tile masked out

    int m0 = mtile * 128;
    int n0 = ntile * 128;

    __shared__ unsigned short smemA[2 * 128 * 32];   // 2 x 8 KB
    __shared__ unsigned short smemB[2 * 128 * 32];   // 2 x 8 KB

    int tid  = threadIdx.x;
    int wid  = tid >> 6;
    int lane = tid & 63;
    int lane15 = lane & 15;
    int quad   = lane >> 4;
    int wave_m = (wid >> 1) * 64;
    int wave_n = (wid & 1) * 64;

    // staging chunk map: chunk c -> row m=c>>2, slot cp=c&3, global k-chunk
    // q = cp ^ ((m>>1)&3)  (XOR swizzle -> 2-way-free LDS access)
    int cA0 = tid, cA1 = tid + 256;
    int mA0 = cA0 >> 2, cp0 = cA0 & 3, q0 = cp0 ^ ((mA0 >> 1) & 3);
    int mA1 = cA1 >> 2, cp1 = cA1 & 3, q1 = cp1 ^ ((mA1 >> 1) & 3);

    const char* gA0 = (const char*)Sb  + (size_t)(m0 + mA0) * (S_*2) + q0 * 16;
    const char* gA1 = (const char*)Sb  + (size_t)(m0 + mA1) * (S_*2) + q1 * 16;
    const char* gB0 = (const char*)W1T + (size_t)(n0 + mA0) * (S_*2) + q0 * 16;
    const char* gB1 = (const char*)W1T + (size_t)(n0 + mA1) * (S_*2) + q1 * 16;
    char* lwA0 = (char*)smemA + cA0 * 16;   // buf0 write addrs; buf1 = +8192
    char* lwA1 = (char*)smemA + cA1 * 16;
    char* lwB0 = (char*)smemB + cA0 * 16;
    char* lwB1 = (char*)smemB + cA1 * 16;

    // fragment read offsets within a buffer (in shorts)
    int aOff[4], bOff[4];
#pragma unroll
    for (int s = 0; s < 4; s++) {
        int ml = wave_m + s * 16 + lane15;
        aOff[s] = ml * 32 + (quad ^ ((ml >> 1) & 3)) * 8;
        int nl = wave_n + s * 16 + lane15;
        bOff[s] = nl * 32 + (quad ^ ((nl >> 1) & 3)) * 8;
    }

    float4v acc[4][4] = {};
    short8 sA0[3], sA1[3], sB0[3], sB1[3];   // 3 register sets -> distance-2 pipeline

    // prologue: issue loads for iters 0,1,2 (constant offsets, monotone vmcnt order)
#pragma unroll
    for (int p = 0; p < 3; p++) {
        sA0[p] = *(const short8*)(gA0 + p * 64);
        sA1[p] = *(const short8*)(gA1 + p * 64);
        sB0[p] = *(const short8*)(gB0 + p * 64);
        sB1[p] = *(const short8*)(gB1 + p * 64);
    }
    // stage iter 0 into buf0 (compiler waits vmcnt only for set 0)
    *(short8*)lwA0 = sA0[0]; *(short8*)lwA1 = sA1[0];
    *(short8*)lwB0 = sB0[0]; *(short8*)lwB1 = sB1[0];

#pragma unroll
    for (int j = 0; j < NITER; j++) {
        __syncthreads();   // buf[j&1] staged (lgkmcnt only -- no global drain)
        // refill the set just consumed: data for iter j+3, in flight for 2 sub-iters
        if (j + 3 < NITER) {
            sA0[j % 3] = *(const short8*)(gA0 + (j + 3) * 64);
            sA1[j % 3] = *(const short8*)(gA1 + (j + 3) * 64);
            sB0[j % 3] = *(const short8*)(gB0 + (j + 3) * 64);
            sB1[j % 3] = *(const short8*)(gB1 + (j + 3) * 64);
        }
        // stage iter j+1 into the other buffer
        if (j + 1 < NITER) {
            int nb = ((j + 1) & 1) * 8192;
            *(short8*)(lwA0 + nb) = sA0[(j + 1) % 3];
            *(short8*)(lwA1 + nb) = sA1[(j + 1) % 3];
            *(short8*)(lwB0 + nb) = sB0[(j + 1) % 3];
            *(short8*)(lwB1 + nb) = sB1[(j + 1) % 3];
        }
        // compute iter j from buf[j&1]
        const unsigned short* aP = smemA + (j & 1) * 4096;
        const unsigned short* bP = smemB + (j & 1) * 4096;
        short8 af[4], bf[4];
#pragma unroll
        for (int s = 0; s < 4; s++) {
            af[s] = *(const short8*)(aP + aOff[s]);
            bf[s] = *(const short8*)(bP + bOff[s]);
        }
#pragma unroll
        for (int i = 0; i < 4; i++)
#pragma unroll
            for (int jj = 0; jj < 4; jj++)
                acc[i][jj] = __builtin_amdgcn_mfma_f32_16x16x32_bf16(af[i], bf[jj], acc[i][jj], 0, 0, 0);
    }

    // ---- fused epilogue: relu(h) @ W2[:,0:4], shuffle-reduce, atomicAdd ----
    float4v w2r[4];
    float   b1v[4];
#pragma unroll
    for (int ns = 0; ns < 4; ns++) {
        int n_g = n0 + wave_n + ns * 16 + lane15;
        w2r[ns] = *(const float4v*)(W2 + (size_t)n_g * 32);
        b1v[ns] = b1[n_g];
    }
#pragma unroll
    for (int ms = 0; ms < 4; ms++) {
        float p[4][4];
#pragma unroll
        for (int r = 0; r < 4; r++)
#pragma unroll
            for (int c = 0; c < 4; c++) p[r][c] = 0.f;
#pragma unroll
        for (int ns = 0; ns < 4; ns++) {
            float4v av = acc[ms][ns];
#pragma unroll
            for (int r = 0; r < 4; r++) {
                float h = av[r] + b1v[ns];
                h = h > 0.f ? h : 0.f;
                p[r][0] += h * w2r[ns][0];
                p[r][1] += h * w2r[ns][1];
                p[r][2] += h * w2r[ns][2];
                p[r][3] += h * w2r[ns][3];
            }
        }
#pragma unroll
        for (int off = 1; off < 16; off <<= 1)
#pragma unroll
            for (int r = 0; r < 4; r++)
#pragma unroll
                for (int c = 0; c < 4; c++)
                    p[r][c] += __shfl_xor(p[r][c], off);
        if (lane15 < 4) {
            int c = lane15;
#pragma unroll
            for (int r = 0; r < 4; r++) {
                int mg = m0 + wave_m + ms * 16 + quad * 4 + r;
                atomicAdd(&zbuf[(size_t)mg * 4 + c], p[r][c]);
            }
        }
    }
}

// ---- log-softmax gather + masked sum straight into d_out (zeroed beforehand) ----
__global__ __launch_bounds__(128) void reduce_logp_kernel(
        const float* __restrict__ zbuf,
        const int*   __restrict__ actions,
        const int*   __restrict__ lengths,
        const float* __restrict__ b2,
        float*       __restrict__ out)
{
    int b = blockIdx.x;
    int t = blockIdx.y * 128 + threadIdx.x;
    int len = lengths[b];
    float local = 0.f;
    if (t < MAXT && t < len) {
        int row = b * TP1 + t;
        float4v z = *(const float4v*)(zbuf + (size_t)row * 4);
        float z0 = z[0] + b2[0], z1 = z[1] + b2[1], z2 = z[2] + b2[2], z3 = z[3] + b2[3];
        float mx = fmaxf(fmaxf(z0, z1), fmaxf(z2, z3));
        float se = expf(z0 - mx) + expf(z1 - mx) + expf(z2 - mx) + expf(z3 - mx);
        int a = actions[b * MAXT + t];
        float za = (a == 0) ? z0 : (a == 1) ? z1 : (a == 2) ? z2 : z3;
        local = (za - mx) - logf(se);
    }
#pragma unroll
    for (int off = 32; off > 0; off >>= 1) local += __shfl_xor(local, off);
    __shared__ float wsum[2];
    if ((threadIdx.x & 63) == 0) wsum[threadIdx.x >> 6] = local;
    __syncthreads();
    if (threadIdx.x == 0) atomicAdd(out, -(wsum[0] + wsum[1]));   // negate here: out = -sum(logp)
}

extern "C" void kernel_launch(void* const* d_in, const int* in_sizes, int n_in,
                              void* d_out, int out_size, void* d_ws, size_t ws_size,
                              hipStream_t stream) {
    const float* s       = (const float*)d_in[0];  // (64,512,1024) fp32
    const int*   actions = (const int*)  d_in[1];  // (64,511)
    const int*   lengths = (const int*)  d_in[2];  // (64,)
    const float* W1      = (const float*)d_in[3];  // (1024,4096)
    const float* b1      = (const float*)d_in[4];  // (4096,)
    const float* W2      = (const float*)d_in[5];  // (4096,32)
    const float* b2      = (const float*)d_in[6];  // (32,)

    char* ws = (char*)d_ws;
    float*          zbuf = (float*)ws;             // [0, 512KB)
    unsigned short* Sb   = (unsigned short*)(ws + SBF_OFF);
    unsigned short* W1T  = (unsigned short*)(ws + W1T_OFF);

    // zero z-buffer and output accumulator (ws/out poisoned 0xAA before every launch)
    hipMemsetAsync(ws, 0, ZBUF_BYTES, stream);
    hipMemsetAsync(d_out, 0, sizeof(float), stream);

    // merged pre-pass: s->bf16 (live rows) + W1->W1T bf16
    prep_kernel<<<dim3(16384 + 4096), 256, 0, stream>>>(s, W1, lengths, Sb, W1T);
    // fused GEMM + relu + W2[:,0:4] projection (XCD-swizzled 1D grid)
    gemm_fused_kernel<<<dim3(8192), 256, 0, stream>>>(Sb, W1T, b1, W2, lengths, zbuf);
    // log-softmax gather + masked sum -> d_out
    reduce_logp_kernel<<<dim3(B_, 4), 128, 0, stream>>>(zbuf, actions, lengths, b2, (float*)d_out);
}

// Round 6
// 471.638 us; speedup vs baseline: 1.3053x; 1.0107x over previous
//
#include <hip/hip_runtime.h>
#include <hip/hip_bf16.h>
#include <math.h>

// Problem constants
#define B_    64
#define MAXT  511
#define TP1   512
#define S_    1024
#define H_    4096
#define M_TOTAL (B_*TP1)   // 32768 rows
#define NITER (S_/32)      // 32 K-iterations

typedef __attribute__((ext_vector_type(8))) short  short8;   // 8 bf16 = 4 VGPRs (MFMA A/B frag)
typedef __attribute__((ext_vector_type(4))) float  float4v;  // MFMA C/D frag

// ---- workspace layout (bytes) ----
// zbuf [0, 512KB) -- Sb MUST start past it
#define ZBUF_BYTES ((size_t)M_TOTAL*4*sizeof(float))   // 524288
#define SBF_OFF    0x81000                             // 528384 >= ZBUF_BYTES
#define SBF_BYTES  ((size_t)M_TOTAL*S_*2)
#define W1T_OFF    (SBF_OFF + SBF_BYTES)

static __device__ __forceinline__ unsigned short f2bf(float f) {
    unsigned int u = __float_as_uint(f);
    u = u + 0x7fffu + ((u >> 16) & 1u);   // round-to-nearest-even
    return (unsigned short)(u >> 16);
}

// ---- merged pre-pass ----
// blocks [0,16384): s fp32 -> bf16, two live rows per block (wave-uniform skip)
// blocks [16384,16384+4096): W1 (S x H fp32) -> W1T (H x S bf16) 32x32 LDS transpose
// fp32 inputs are read NON-TEMPORALLY: they are one-shot streams and must not
// evict the reused Sb/W1T working set (~83 MB) from the 256 MB L3.
__global__ __launch_bounds__(256) void prep_kernel(const float* __restrict__ s,
                                                   const float* __restrict__ W1,
                                                   const int*   __restrict__ lengths,
                                                   unsigned short* __restrict__ Sb,
                                                   unsigned short* __restrict__ W1T) {
    int bid = blockIdx.x;
    if (bid < 16384) {
        int row = 2 * bid + (threadIdx.x >> 7);          // waves 0,1 -> row; waves 2,3 -> row+1
        int b = row >> 9, t = row & 511;
        if (t >= lengths[b]) return;                     // dead row: never read downstream
        size_t idx = (size_t)row * S_ + (threadIdx.x & 127) * 8;
        float4v f0 = __builtin_nontemporal_load((const float4v*)(s + idx));
        float4v f1 = __builtin_nontemporal_load((const float4v*)(s + idx + 4));
        short8 o;
        o[0] = (short)f2bf(f0[0]); o[1] = (short)f2bf(f0[1]);
        o[2] = (short)f2bf(f0[2]); o[3] = (short)f2bf(f0[3]);
        o[4] = (short)f2bf(f1[0]); o[5] = (short)f2bf(f1[1]);
        o[6] = (short)f2bf(f1[2]); o[7] = (short)f2bf(f1[3]);
        *(short8*)(Sb + idx) = o;
    } else {
        __shared__ float tile[32][33];
        int tb = bid - 16384;
        int h0 = (tb & 127) * 32;                        // H dim
        int k0 = (tb >> 7) * 32;                         // S dim
        int tx = threadIdx.x & 31, ty = threadIdx.x >> 5; // 32 x 8
        for (int r = ty; r < 32; r += 8)
            tile[r][tx] = __builtin_nontemporal_load(&W1[(size_t)(k0 + r) * H_ + h0 + tx]);
        __syncthreads();
        for (int r = ty; r < 32; r += 8)
            W1T[(size_t)(h0 + r) * S_ + k0 + tx] = f2bf(tile[tx][r]);
    }
}

// ---- main fused GEMM ----
// 128x128 tile, BK=32, buffer_load->VGPR->ds_write staging (no vmcnt drain at
// barriers), 3 register sets = prefetch distance 2, full 32-iter unroll.
// __launch_bounds__(256,3): ~170 regs/wave -- fits acc(64 AGPR)+staging(48)+
// frags(32)+addr without scratch spills (R4's (256,4)=128 regs spilled ~250 MB).
// XCD swizzle: xcd = id&7 owns ntiles [4x,4x+4) -> 1 MB of W1T stays L2-resident.
__global__ __launch_bounds__(256, 3) void gemm_fused_kernel(
        const unsigned short* __restrict__ Sb,    // M x S bf16
        const unsigned short* __restrict__ W1T,   // H x S bf16
        const float* __restrict__ b1,             // H
        const float* __restrict__ W2,             // H x 32 fp32 (cols 0..3 used)
        const int*   __restrict__ lengths,        // B
        float*       __restrict__ zbuf)           // M x 4
{
    int id   = blockIdx.x;
    int xcd  = id & 7;
    int slot = id >> 3;                  // 0..1023
    int ntile = xcd * 4 + (slot & 3);    // 0..31
    int mtile = slot >> 2;               // 0..255

    int b  = mtile >> 2;
    int t0 = (mtile & 3) * 128;
    if (lengths[b] <= t0) return;        // whole tile masked out

    int m0 = mtile * 128;
    int n0 = ntile * 128;

    __shared__ unsigned short smemA[2 * 128 * 32];   // 2 x 8 KB
    __shared__ unsigned short smemB[2 * 128 * 32];   // 2 x 8 KB

    int tid  = threadIdx.x;
    int wid  = tid >> 6;
    int lane = tid & 63;
    int lane15 = lane & 15;
    int quad   = lane >> 4;
    int wave_m = (wid >> 1) * 64;
    int wave_n = (wid & 1) * 64;

    // staging chunk map: chunk c -> row m=c>>2, slot cp=c&3, global k-chunk
    // q = cp ^ ((m>>1)&3)  (XOR swizzle -> 2-way-free LDS access)
    int cA0 = tid, cA1 = tid + 256;
    int mA0 = cA0 >> 2, cp0 = cA0 & 3, q0 = cp0 ^ ((mA0 >> 1) & 3);
    int mA1 = cA1 >> 2, cp1 = cA1 & 3, q1 = cp1 ^ ((mA1 >> 1) & 3);

    const char* gA0 = (const char*)Sb  + (size_t)(m0 + mA0) * (S_*2) + q0 * 16;
    const char* gA1 = (const char*)Sb  + (size_t)(m0 + mA1) * (S_*2) + q1 * 16;
    const char* gB0 = (const char*)W1T + (size_t)(n0 + mA0) * (S_*2) + q0 * 16;
    const char* gB1 = (const char*)W1T + (size_t)(n0 + mA1) * (S_*2) + q1 * 16;
    char* lwA0 = (char*)smemA + cA0 * 16;   // buf0 write addrs; buf1 = +8192
    char* lwA1 = (char*)smemA + cA1 * 16;
    char* lwB0 = (char*)smemB + cA0 * 16;
    char* lwB1 = (char*)smemB + cA1 * 16;

    // fragment read offsets within a buffer (in shorts)
    int aOff[4], bOff[4];
#pragma unroll
    for (int s = 0; s < 4; s++) {
        int ml = wave_m + s * 16 + lane15;
        aOff[s] = ml * 32 + (quad ^ ((ml >> 1) & 3)) * 8;
        int nl = wave_n + s * 16 + lane15;
        bOff[s] = nl * 32 + (quad ^ ((nl >> 1) & 3)) * 8;
    }

    float4v acc[4][4] = {};
    short8 sA0[3], sA1[3], sB0[3], sB1[3];   // 3 register sets -> distance-2 pipeline

    // prologue: issue loads for iters 0,1,2 (constant offsets, monotone vmcnt order)
#pragma unroll
    for (int p = 0; p < 3; p++) {
        sA0[p] = *(const short8*)(gA0 + p * 64);
        sA1[p] = *(const short8*)(gA1 + p * 64);
        sB0[p] = *(const short8*)(gB0 + p * 64);
        sB1[p] = *(const short8*)(gB1 + p * 64);
    }
    // stage iter 0 into buf0 (compiler waits vmcnt only for set 0)
    *(short8*)lwA0 = sA0[0]; *(short8*)lwA1 = sA1[0];
    *(short8*)lwB0 = sB0[0]; *(short8*)lwB1 = sB1[0];

#pragma unroll
    for (int j = 0; j < NITER; j++) {
        __syncthreads();   // buf[j&1] staged (lgkmcnt only -- no global drain)
        // refill the set just consumed: data for iter j+3, in flight for 2 sub-iters
        if (j + 3 < NITER) {
            sA0[j % 3] = *(const short8*)(gA0 + (j + 3) * 64);
            sA1[j % 3] = *(const short8*)(gA1 + (j + 3) * 64);
            sB0[j % 3] = *(const short8*)(gB0 + (j + 3) * 64);
            sB1[j % 3] = *(const short8*)(gB1 + (j + 3) * 64);
        }
        // stage iter j+1 into the other buffer
        if (j + 1 < NITER) {
            int nb = ((j + 1) & 1) * 8192;
            *(short8*)(lwA0 + nb) = sA0[(j + 1) % 3];
            *(short8*)(lwA1 + nb) = sA1[(j + 1) % 3];
            *(short8*)(lwB0 + nb) = sB0[(j + 1) % 3];
            *(short8*)(lwB1 + nb) = sB1[(j + 1) % 3];
        }
        // compute iter j from buf[j&1]
        const unsigned short* aP = smemA + (j & 1) * 4096;
        const unsigned short* bP = smemB + (j & 1) * 4096;
        short8 af[4], bf[4];
#pragma unroll
        for (int s = 0; s < 4; s++) {
            af[s] = *(const short8*)(aP + aOff[s]);
            bf[s] = *(const short8*)(bP + bOff[s]);
        }
#pragma unroll
        for (int i = 0; i < 4; i++)
#pragma unroll
            for (int jj = 0; jj < 4; jj++)
                acc[i][jj] = __builtin_amdgcn_mfma_f32_16x16x32_bf16(af[i], bf[jj], acc[i][jj], 0, 0, 0);
    }

    // ---- fused epilogue: relu(h) @ W2[:,0:4], shuffle-reduce, atomicAdd ----
    float4v w2r[4];
    float   b1v[4];
#pragma unroll
    for (int ns = 0; ns < 4; ns++) {
        int n_g = n0 + wave_n + ns * 16 + lane15;
        w2r[ns] = *(const float4v*)(W2 + (size_t)n_g * 32);
        b1v[ns] = b1[n_g];
    }
#pragma unroll
    for (int ms = 0; ms < 4; ms++) {
        float p[4][4];
#pragma unroll
        for (int r = 0; r < 4; r++)
#pragma unroll
            for (int c = 0; c < 4; c++) p[r][c] = 0.f;
#pragma unroll
        for (int ns = 0; ns < 4; ns++) {
            float4v av = acc[ms][ns];
#pragma unroll
            for (int r = 0; r < 4; r++) {
                float h = av[r] + b1v[ns];
                h = h > 0.f ? h : 0.f;
                p[r][0] += h * w2r[ns][0];
                p[r][1] += h * w2r[ns][1];
                p[r][2] += h * w2r[ns][2];
                p[r][3] += h * w2r[ns][3];
            }
        }
#pragma unroll
        for (int off = 1; off < 16; off <<= 1)
#pragma unroll
            for (int r = 0; r < 4; r++)
#pragma unroll
                for (int c = 0; c < 4; c++)
                    p[r][c] += __shfl_xor(p[r][c], off);
        if (lane15 < 4) {
            int c = lane15;
#pragma unroll
            for (int r = 0; r < 4; r++) {
                int mg = m0 + wave_m + ms * 16 + quad * 4 + r;
                atomicAdd(&zbuf[(size_t)mg * 4 + c], p[r][c]);
            }
        }
    }
}

// ---- log-softmax gather + masked sum straight into d_out (zeroed beforehand) ----
__global__ __launch_bounds__(128) void reduce_logp_kernel(
        const float* __restrict__ zbuf,
        const int*   __restrict__ actions,
        const int*   __restrict__ lengths,
        const float* __restrict__ b2,
        float*       __restrict__ out)
{
    int b = blockIdx.x;
    int t = blockIdx.y * 128 + threadIdx.x;
    int len = lengths[b];
    float local = 0.f;
    if (t < MAXT && t < len) {
        int row = b * TP1 + t;
        float4v z = *(const float4v*)(zbuf + (size_t)row * 4);
        float z0 = z[0] + b2[0], z1 = z[1] + b2[1], z2 = z[2] + b2[2], z3 = z[3] + b2[3];
        float mx = fmaxf(fmaxf(z0, z1), fmaxf(z2, z3));
        float se = expf(z0 - mx) + expf(z1 - mx) + expf(z2 - mx) + expf(z3 - mx);
        int a = actions[b * MAXT + t];
        float za = (a == 0) ? z0 : (a == 1) ? z1 : (a == 2) ? z2 : z3;
        local = (za - mx) - logf(se);
    }
#pragma unroll
    for (int off = 32; off > 0; off >>= 1) local += __shfl_xor(local, off);
    __shared__ float wsum[2];
    if ((threadIdx.x & 63) == 0) wsum[threadIdx.x >> 6] = local;
    __syncthreads();
    if (threadIdx.x == 0) atomicAdd(out, -(wsum[0] + wsum[1]));   // negate here: out = -sum(logp)
}

extern "C" void kernel_launch(void* const* d_in, const int* in_sizes, int n_in,
                              void* d_out, int out_size, void* d_ws, size_t ws_size,
                              hipStream_t stream) {
    const float* s       = (const float*)d_in[0];  // (64,512,1024) fp32
    const int*   actions = (const int*)  d_in[1];  // (64,511)
    const int*   lengths = (const int*)  d_in[2];  // (64,)
    const float* W1      = (const float*)d_in[3];  // (1024,4096)
    const float* b1      = (const float*)d_in[4];  // (4096,)
    const float* W2      = (const float*)d_in[5];  // (4096,32)
    const float* b2      = (const float*)d_in[6];  // (32,)

    char* ws = (char*)d_ws;
    float*          zbuf = (float*)ws;             // [0, 512KB)
    unsigned short* Sb   = (unsigned short*)(ws + SBF_OFF);
    unsigned short* W1T  = (unsigned short*)(ws + W1T_OFF);

    // zero z-buffer and output accumulator (ws/out poisoned 0xAA before every launch)
    hipMemsetAsync(ws, 0, ZBUF_BYTES, stream);
    hipMemsetAsync(d_out, 0, sizeof(float), stream);

    // merged pre-pass: s->bf16 (live rows, nt loads) + W1->W1T bf16
    prep_kernel<<<dim3(16384 + 4096), 256, 0, stream>>>(s, W1, lengths, Sb, W1T);
    // fused GEMM + relu + W2[:,0:4] projection (XCD-swizzled 1D grid)
    gemm_fused_kernel<<<dim3(8192), 256, 0, stream>>>(Sb, W1T, b1, W2, lengths, zbuf);
    // log-softmax gather + masked sum -> d_out
    reduce_logp_kernel<<<dim3(B_, 4), 128, 0, stream>>>(zbuf, actions, lengths, b2, (float*)d_out);
}